// Round 2
// baseline (317.163 us; speedup 1.0000x reference)
//
#include <hip/hip_runtime.h>
#include <math.h>

#define BDIM 4
#define CDIM 64
#define HDIM 128
#define WDIM 128
#define PLANE (HDIM*WDIM)   // 16384
#define CHW (CDIM*PLANE)    // 1048576

// K1: per (b,h): channel-residue sums T[b][h][w][4] and row means xmw[b][c][h]
__global__ void k1_T_rowmean(const float* __restrict__ x, float* __restrict__ T,
                             float* __restrict__ xmw) {
  int bid = blockIdx.x;            // b*128 + h
  int b = bid >> 7, h = bid & 127;
  int lane = threadIdx.x;          // 64 threads (1 wave)
  const float* xp = x + (size_t)b * CHW + h * WDIM;
  float tr[4] = {0,0,0,0}, ur[4] = {0,0,0,0};
  for (int c0 = 0; c0 < CDIM; c0 += 4) {
#pragma unroll
    for (int k = 0; k < 4; k++) {
      int c = c0 + k;
      float v0 = xp[c * PLANE + lane];
      float v1 = xp[c * PLANE + lane + 64];
      tr[k] += v0; ur[k] += v1;
      float s = v0 + v1;
#pragma unroll
      for (int off = 32; off; off >>= 1) s += __shfl_xor(s, off);
      if (lane == 0) xmw[(b * CDIM + c) * HDIM + h] = s * (1.f / WDIM);
    }
  }
  float4* Tp = (float4*)(T + (size_t)(b * HDIM + h) * WDIM * 4);
  Tp[lane]      = make_float4(tr[0], tr[1], tr[2], tr[3]);
  Tp[lane + 64] = make_float4(ur[0], ur[1], ur[2], ur[3]);
}

// K2: column means xmh[b][c][w] (mean over h)
__global__ void k2_colmean(const float* __restrict__ x, float* __restrict__ xmh) {
  int bid = blockIdx.x;            // b*64 + c
  int b = bid >> 6, c = bid & 63;
  int w = threadIdx.x;             // 128 threads
  const float* xp = x + (size_t)(b * CDIM + c) * PLANE;
  float s = 0.f;
  for (int h = 0; h < HDIM; h++) s += xp[h * WDIM + w];
  xmh[(b * CDIM + c) * WDIM + w] = s * (1.f / HDIM);
}

// K3: enc_h[o][h][bb] = b1[o] + sum_i W1[o,i]*xmw[bb,i,h]; same for enc_w
__global__ void k3_enc(const float* __restrict__ W1, const float* __restrict__ bias1,
                       const float* __restrict__ W2, const float* __restrict__ bias2,
                       const float* __restrict__ xmw, const float* __restrict__ xmh,
                       float* __restrict__ ench, float* __restrict__ encw) {
  int bid = blockIdx.x;            // 0..255: [0,128) h-branch, [128,256) w-branch
  int t = threadIdx.x;             // 256
  int o = t >> 2, bb = t & 3;
  if (bid < HDIM) {
    int h = bid;
    float s = bias1[o];
    for (int i = 0; i < CDIM; i++) s += W1[o * CDIM + i] * xmw[(bb * CDIM + i) * HDIM + h];
    ench[(o * HDIM + h) * 4 + bb] = s;
  } else {
    int w = bid - HDIM;
    float s = bias2[o];
    for (int i = 0; i < CDIM; i++) s += W2[o * CDIM + i] * xmh[(bb * CDIM + i) * WDIM + w];
    encw[(o * WDIM + w) * 4 + bb] = s;
  }
}

// K4: per (b,c) plane: 4-way softmax probs for both branches.
// Ph[c2][n][r] = softmax_r(e)/W for (c2,n) <-> (b,c,w);  Pw analogous with h.
__global__ void k4_probs(const float* __restrict__ x, const float* __restrict__ ench,
                         const float* __restrict__ encw, float* __restrict__ Ph,
                         float* __restrict__ Pw) {
  __shared__ float plane[HDIM * WDIM];   // XOR-swizzled: [h][w ^ (h&31)]
  int bid = blockIdx.x;            // b*64 + c
  int b = bid >> 6, c = bid & 63;
  int t = threadIdx.x;             // 128
  const float* xp = x + (size_t)(b * CDIM + c) * PLANE;
  for (int h = 0; h < HDIM; h++) plane[h * WDIM + (t ^ (h & 31))] = xp[h * WDIM + t];
  __syncthreads();
  // h-branch: t = w
  {
    int c2 = (b * HDIM + t) >> 3;
    const float4* E = (const float4*)ench + c2 * HDIM;
    float e0 = 0, e1 = 0, e2 = 0, e3 = 0;
    for (int h = 0; h < HDIM; h++) {
      float v = plane[h * WDIM + (t ^ (h & 31))];
      float4 e = E[h];
      e0 += v * e.x; e1 += v * e.y; e2 += v * e.z; e3 += v * e.w;
    }
    float m = fmaxf(fmaxf(e0, e1), fmaxf(e2, e3));
    float p0 = expf(e0 - m), p1 = expf(e1 - m), p2 = expf(e2 - m), p3 = expf(e3 - m);
    float sc = 1.f / ((p0 + p1 + p2 + p3) * (float)WDIM);
    ((float4*)Ph)[c2 * 512 + (t & 7) * 64 + c] = make_float4(p0 * sc, p1 * sc, p2 * sc, p3 * sc);
  }
  // w-branch: t = h
  {
    int c2 = (b * HDIM + t) >> 3;
    const float4* E = (const float4*)encw + c2 * WDIM;
    float e0 = 0, e1 = 0, e2 = 0, e3 = 0;
    for (int w = 0; w < WDIM; w++) {
      float v = plane[t * WDIM + (w ^ (t & 31))];
      float4 e = E[w];
      e0 += v * e.x; e1 += v * e.y; e2 += v * e.z; e3 += v * e.w;
    }
    float m = fmaxf(fmaxf(e0, e1), fmaxf(e2, e3));
    float p0 = expf(e0 - m), p1 = expf(e1 - m), p2 = expf(e2 - m), p3 = expf(e3 - m);
    float sc = 1.f / ((p0 + p1 + p2 + p3) * (float)HDIM);
    ((float4*)Pw)[c2 * 512 + (t & 7) * 64 + c] = make_float4(p0 * sc, p1 * sc, p2 * sc, p3 * sc);
  }
}

// K4b: group sums Gh[c2][h][4], Gw[c2][w][4] from T
__global__ void k4b_groups(const float* __restrict__ T, float* __restrict__ Gh,
                           float* __restrict__ Gw) {
  int c2 = blockIdx.x;             // 64
  int t = threadIdx.x;             // 128
  int b = c2 >> 4;
  int w0 = (c2 & 15) * 8;          // h0 == w0
  const float4* T4 = (const float4*)T;
  float4 s = make_float4(0, 0, 0, 0);
#pragma unroll
  for (int dw = 0; dw < 8; dw++) {
    float4 v = T4[(b * HDIM + t) * WDIM + w0 + dw];
    s.x += v.x; s.y += v.y; s.z += v.z; s.w += v.w;
  }
  ((float4*)Gh)[c2 * HDIM + t] = s;
  float4 s2 = make_float4(0, 0, 0, 0);
#pragma unroll
  for (int dh = 0; dh < 8; dh++) {
    float4 v = T4[(b * HDIM + w0 + dh) * WDIM + t];
    s2.x += v.x; s2.y += v.y; s2.z += v.z; s2.w += v.w;
  }
  ((float4*)Gw)[c2 * WDIM + t] = s2;
}

// K5: out = gamma*(aug_h + aug_w) + x
__global__ void k5_out(const float* __restrict__ x, const float* __restrict__ Ph,
                       const float* __restrict__ Pw, const float* __restrict__ Gh,
                       const float* __restrict__ Gw, const float* __restrict__ gamma,
                       float* __restrict__ outb) {
  int bid = blockIdx.x;            // b*64 + c
  int b = bid >> 6, c = bid & 63;
  int t = threadIdx.x;             // 128 (= w)
  float g = gamma[0];
  int c2h = (b * HDIM + t) >> 3;
  float4 ph = ((const float4*)Ph)[c2h * 512 + (t & 7) * 64 + c];
  const float* xp = x + (size_t)(b * CDIM + c) * PLANE;
  float* op = outb + (size_t)(b * CDIM + c) * PLANE;
  for (int h = 0; h < HDIM; h++) {
    int c2w = (b * HDIM + h) >> 3;
    float4 pw = ((const float4*)Pw)[c2w * 512 + (h & 7) * 64 + c];
    float4 gh = ((const float4*)Gh)[c2h * HDIM + h];
    float4 gw = ((const float4*)Gw)[c2w * WDIM + t];
    float val = ph.x * gh.x + ph.y * gh.y + ph.z * gh.z + ph.w * gh.w
              + pw.x * gw.x + pw.y * gw.y + pw.z * gw.z + pw.w * gw.w;
    op[h * WDIM + t] = fmaf(g, val, xp[h * WDIM + t]);
  }
}

// K6: 3x3 conv (SAME, no bias). block = (b, 16-o tile, 8-row strip), 256 thr.
__global__ __launch_bounds__(256) void k6_conv(const float* __restrict__ outb,
                                               const float* __restrict__ Wc,
                                               float* __restrict__ yb) {
  __shared__ float strip[10 * WDIM];
  int bid = blockIdx.x;
  int hs = bid & 15, ot = (bid >> 4) & 3, b = bid >> 6;
  int hbase = hs * 8, obase = ot * 16;
  int t = threadIdx.x;
  int tw = t & 127, th2 = t >> 7;
  float acc[4][16];
#pragma unroll
  for (int k = 0; k < 4; k++)
#pragma unroll
    for (int o = 0; o < 16; o++) acc[k][o] = 0.f;

  const float* inb = outb + (size_t)b * CHW;
  float pre[5];
#pragma unroll
  for (int k = 0; k < 5; k++) {
    int idx = k * 256 + t; int row = idx >> 7, ww = idx & 127; int gh = hbase - 1 + row;
    pre[k] = (gh >= 0 && gh < HDIM) ? inb[gh * WDIM + ww] : 0.f;
  }
  for (int i = 0; i < CDIM; i++) {
    __syncthreads();
#pragma unroll
    for (int k = 0; k < 5; k++) strip[k * 256 + t] = pre[k];
    __syncthreads();
    if (i < CDIM - 1) {
#pragma unroll
      for (int k = 0; k < 5; k++) {
        int idx = k * 256 + t; int row = idx >> 7, ww = idx & 127; int gh = hbase - 1 + row;
        pre[k] = (gh >= 0 && gh < HDIM) ? inb[(i + 1) * PLANE + gh * WDIM + ww] : 0.f;
      }
    }
    float nb[9][3];
#pragma unroll
    for (int r = 0; r < 9; r++) {
      int row = th2 + r;
      nb[r][0] = (tw > 0)   ? strip[row * WDIM + tw - 1] : 0.f;
      nb[r][1] =              strip[row * WDIM + tw];
      nb[r][2] = (tw < 127) ? strip[row * WDIM + tw + 1] : 0.f;
    }
    const float* wp = Wc + ((size_t)obase * CDIM + i) * 9;
#pragma unroll
    for (int o = 0; o < 16; o++) {
      const float* w9 = wp + (size_t)o * CDIM * 9;
      float w0 = w9[0], w1 = w9[1], w2 = w9[2], w3 = w9[3], w4 = w9[4],
            w5 = w9[5], w6 = w9[6], w7 = w9[7], w8 = w9[8];
#pragma unroll
      for (int k = 0; k < 4; k++) {
        acc[k][o] += nb[2*k  ][0] * w0 + nb[2*k  ][1] * w1 + nb[2*k  ][2] * w2
                   + nb[2*k+1][0] * w3 + nb[2*k+1][1] * w4 + nb[2*k+1][2] * w5
                   + nb[2*k+2][0] * w6 + nb[2*k+2][1] * w7 + nb[2*k+2][2] * w8;
      }
    }
  }
#pragma unroll
  for (int k = 0; k < 4; k++) {
    int h = hbase + th2 + 2 * k;
#pragma unroll
    for (int o = 0; o < 16; o++)
      yb[((size_t)(b * CDIM + obase + o) * HDIM + h) * WDIM + tw] = acc[k][o];
  }
}

// K7a: per (b, o) plane partial sums for BN stats
__global__ void k7a_stats(const float* __restrict__ yb, float* __restrict__ part) {
  int bid = blockIdx.x;            // b*64 + o
  int b = bid >> 6, o = bid & 63;
  int t = threadIdx.x;             // 256
  const float* yp = yb + (size_t)(b * CDIM + o) * PLANE;
  float s = 0.f, ss = 0.f;
  for (int r = t; r < PLANE; r += 256) {
    float v = yp[r];
    s += v; ss += v * v;
  }
#pragma unroll
  for (int off = 32; off; off >>= 1) { s += __shfl_xor(s, off); ss += __shfl_xor(ss, off); }
  __shared__ float sh[8];
  int wid = t >> 6;
  if ((t & 63) == 0) { sh[wid] = s; sh[4 + wid] = ss; }
  __syncthreads();
  if (t == 0) {
    s  = sh[0] + sh[1] + sh[2] + sh[3];
    ss = sh[4] + sh[5] + sh[6] + sh[7];
    part[bid] = s;
    part[256 + bid] = ss;
  }
}

// K7b: finalize mean / rstd per channel
__global__ void k7b_finalize(const float* __restrict__ part, float* __restrict__ stats) {
  int o = threadIdx.x;             // 64
  float s = 0.f, ss = 0.f;
#pragma unroll
  for (int b = 0; b < BDIM; b++) { s += part[b * 64 + o]; ss += part[256 + b * 64 + o]; }
  float n = (float)(BDIM * PLANE);
  float m = s / n;
  float var = ss / n - m * m;
  stats[o] = m;
  stats[64 + o] = rsqrtf(var + 1e-5f);
}

// K8: normalize + affine + ReLU
__global__ void k8_norm(const float* __restrict__ yb, const float* __restrict__ stats,
                        const float* __restrict__ bnw, const float* __restrict__ bnb,
                        float* __restrict__ out) {
  int idx = blockIdx.x * 256 + threadIdx.x;   // float4 index, total 1048576
  int c = (idx >> 12) & 63;                   // (idx*4 / 16384) % 64
  float4 v = ((const float4*)yb)[idx];
  float m = stats[c], rs = stats[64 + c], w = bnw[c], bb = bnb[c];
  v.x = fmaxf(0.f, (v.x - m) * rs * w + bb);
  v.y = fmaxf(0.f, (v.y - m) * rs * w + bb);
  v.z = fmaxf(0.f, (v.z - m) * rs * w + bb);
  v.w = fmaxf(0.f, (v.w - m) * rs * w + bb);
  ((float4*)out)[idx] = v;
}

extern "C" void kernel_launch(void* const* d_in, const int* in_sizes, int n_in,
                              void* d_out, int out_size, void* d_ws, size_t ws_size,
                              hipStream_t stream) {
  const float* x     = (const float*)d_in[0];
  const float* W1    = (const float*)d_in[1];
  const float* b1    = (const float*)d_in[2];
  const float* W2    = (const float*)d_in[3];
  const float* b2    = (const float*)d_in[4];
  const float* Wc    = (const float*)d_in[5];
  const float* bnw   = (const float*)d_in[6];
  const float* bnb   = (const float*)d_in[7];
  const float* gamma = (const float*)d_in[8];
  float* out = (float*)d_out;

  float* ws   = (float*)d_ws;
  float* T    = ws;                 // 262144
  float* xmw  = T    + 262144;      // 32768
  float* xmh  = xmw  + 32768;       // 32768
  float* ench = xmh  + 32768;       // 32768
  float* encw = ench + 32768;       // 32768
  float* Ph   = encw + 32768;       // 131072
  float* Pw   = Ph   + 131072;      // 131072
  float* Gh   = Pw   + 131072;      // 32768
  float* Gw   = Gh   + 32768;       // 32768
  float* outb = Gw   + 32768;       // 4194304
  float* yb   = outb + 4194304;     // 4194304
  float* part = yb   + 4194304;     // 512
  float* stats= part + 512;         // 128

  k1_T_rowmean<<<512, 64, 0, stream>>>(x, T, xmw);
  k2_colmean  <<<256, 128, 0, stream>>>(x, xmh);
  k3_enc      <<<256, 256, 0, stream>>>(W1, b1, W2, b2, xmw, xmh, ench, encw);
  k4_probs    <<<256, 128, 0, stream>>>(x, ench, encw, Ph, Pw);
  k4b_groups  <<<64, 128, 0, stream>>>(T, Gh, Gw);
  k5_out      <<<256, 128, 0, stream>>>(x, Ph, Pw, Gh, Gw, gamma, outb);
  k6_conv     <<<256, 256, 0, stream>>>(outb, Wc, yb);
  k7a_stats   <<<256, 256, 0, stream>>>(yb, part);
  k7b_finalize<<<1, 64, 0, stream>>>(part, stats);
  k8_norm     <<<4096, 256, 0, stream>>>(yb, stats, bnw, bnb, out);
}

// Round 3
// 223.814 us; speedup vs baseline: 1.4171x; 1.4171x over previous
//
#include <hip/hip_runtime.h>
#include <math.h>

#define BDIM 4
#define CDIM 64
#define HDIM 128
#define WDIM 128
#define PLANE (HDIM*WDIM)   // 16384
#define CHW (CDIM*PLANE)    // 1048576

// K1: per (b,h): channel-residue sums T[b][h][w][4] and row means xmw[b][c][h].
// 4 waves/block, each wave owns a 16-channel slice; T combined via LDS.
__global__ __launch_bounds__(256) void k1_T_rowmean(const float* __restrict__ x,
                                                    float* __restrict__ T,
                                                    float* __restrict__ xmw) {
  int bid = blockIdx.x;            // b*128 + h
  int b = bid >> 7, h = bid & 127;
  int t = threadIdx.x;
  int wid = t >> 6, lane = t & 63;
  const float* xp = x + (size_t)b * CHW + h * WDIM;
  float tr[4] = {0,0,0,0}, ur[4] = {0,0,0,0};
#pragma unroll
  for (int cc = 0; cc < 16; cc++) {
    int c = wid * 16 + cc;
    int k = cc & 3;                // c&3 == cc&3 (wid*16 multiple of 4)
    float v0 = xp[c * PLANE + lane];
    float v1 = xp[c * PLANE + lane + 64];
    tr[k] += v0; ur[k] += v1;
    float s = v0 + v1;
#pragma unroll
    for (int off = 32; off; off >>= 1) s += __shfl_xor(s, off);
    if (lane == 0) xmw[(b * CDIM + c) * HDIM + h] = s * (1.f / WDIM);
  }
  __shared__ float4 pt[4][128];    // [wave][w]
  pt[wid][lane]      = make_float4(tr[0], tr[1], tr[2], tr[3]);
  pt[wid][lane + 64] = make_float4(ur[0], ur[1], ur[2], ur[3]);
  __syncthreads();
  if (t < 128) {
    float4 a = pt[0][t], bb = pt[1][t], cvec = pt[2][t], d = pt[3][t];
    float4 s = make_float4(a.x + bb.x + cvec.x + d.x, a.y + bb.y + cvec.y + d.y,
                           a.z + bb.z + cvec.z + d.z, a.w + bb.w + cvec.w + d.w);
    ((float4*)T)[(b * HDIM + h) * WDIM + t] = s;
  }
}

// K2: column means xmh[b][c][w] (mean over h), 2-way h-split
__global__ void k2_colmean(const float* __restrict__ x, float* __restrict__ xmh) {
  int bid = blockIdx.x;            // b*64 + c
  int b = bid >> 6, c = bid & 63;
  int t = threadIdx.x;             // 256
  int tw = t & 127, th2 = t >> 7;
  const float* xp = x + (size_t)(b * CDIM + c) * PLANE;
  float s = 0.f;
  for (int h = th2 * 64; h < th2 * 64 + 64; h++) s += xp[h * WDIM + tw];
  __shared__ float sh[256];
  sh[t] = s;
  __syncthreads();
  if (t < 128) xmh[(b * CDIM + c) * WDIM + t] = (sh[t] + sh[t + 128]) * (1.f / HDIM);
}

// K3: enc_h[o][h][bb] = b1[o] + sum_i W1[o,i]*xmw[bb,i,h]; same for enc_w
__global__ void k3_enc(const float* __restrict__ W1, const float* __restrict__ bias1,
                       const float* __restrict__ W2, const float* __restrict__ bias2,
                       const float* __restrict__ xmw, const float* __restrict__ xmh,
                       float* __restrict__ ench, float* __restrict__ encw) {
  int bid = blockIdx.x;            // 0..255: [0,128) h-branch, [128,256) w-branch
  int t = threadIdx.x;             // 256
  int o = t >> 2, bb = t & 3;
  if (bid < HDIM) {
    int h = bid;
    float s = bias1[o];
    for (int i = 0; i < CDIM; i++) s += W1[o * CDIM + i] * xmw[(bb * CDIM + i) * HDIM + h];
    ench[(o * HDIM + h) * 4 + bb] = s;
  } else {
    int w = bid - HDIM;
    float s = bias2[o];
    for (int i = 0; i < CDIM; i++) s += W2[o * CDIM + i] * xmh[(bb * CDIM + i) * WDIM + w];
    encw[(o * WDIM + w) * 4 + bb] = s;
  }
}

// K4: per (b,c) plane: 4-way softmax probs. 256 threads: waves 0-1 h-branch,
// waves 2-3 w-branch (both read the XOR-swizzled LDS plane).
__global__ __launch_bounds__(256) void k4_probs(const float* __restrict__ x,
                                                const float* __restrict__ ench,
                                                const float* __restrict__ encw,
                                                float* __restrict__ Ph,
                                                float* __restrict__ Pw) {
  __shared__ float plane[HDIM * WDIM];   // [h][w ^ (h&31)]
  int bid = blockIdx.x;            // b*64 + c
  int b = bid >> 6, c = bid & 63;
  int t = threadIdx.x;             // 256
  const float* xp = x + (size_t)(b * CDIM + c) * PLANE;
#pragma unroll 4
  for (int j = 0; j < 64; j++) {
    int idx = j * 256 + t;
    int row = idx >> 7, col = idx & 127;
    plane[row * WDIM + (col ^ (row & 31))] = xp[idx];
  }
  __syncthreads();
  int half = t >> 7, p = t & 127;
  int c2 = (b * HDIM + p) >> 3;
  float e0 = 0, e1 = 0, e2 = 0, e3 = 0;
  if (half == 0) {                 // h-branch: p = w
    const float4* E = (const float4*)ench + c2 * HDIM;
    for (int h = 0; h < HDIM; h++) {
      float v = plane[h * WDIM + (p ^ (h & 31))];
      float4 e = E[h];
      e0 += v * e.x; e1 += v * e.y; e2 += v * e.z; e3 += v * e.w;
    }
  } else {                         // w-branch: p = h
    const float4* E = (const float4*)encw + c2 * WDIM;
    for (int w = 0; w < WDIM; w++) {
      float v = plane[p * WDIM + (w ^ (p & 31))];
      float4 e = E[w];
      e0 += v * e.x; e1 += v * e.y; e2 += v * e.z; e3 += v * e.w;
    }
  }
  float m = fmaxf(fmaxf(e0, e1), fmaxf(e2, e3));
  float p0 = expf(e0 - m), p1 = expf(e1 - m), p2 = expf(e2 - m), p3 = expf(e3 - m);
  float sc = 1.f / ((p0 + p1 + p2 + p3) * 128.f);
  float4* dst = (half == 0) ? (float4*)Ph : (float4*)Pw;
  dst[c2 * 512 + (p & 7) * 64 + c] = make_float4(p0 * sc, p1 * sc, p2 * sc, p3 * sc);
}

// K4b: group sums Gh[c2][h][4], Gw[c2][w][4] from T
__global__ void k4b_groups(const float* __restrict__ T, float* __restrict__ Gh,
                           float* __restrict__ Gw) {
  int c2 = blockIdx.x;             // 64
  int t = threadIdx.x;             // 128
  int b = c2 >> 4;
  int w0 = (c2 & 15) * 8;          // h0 == w0
  const float4* T4 = (const float4*)T;
  float4 s = make_float4(0, 0, 0, 0);
#pragma unroll
  for (int dw = 0; dw < 8; dw++) {
    float4 v = T4[(b * HDIM + t) * WDIM + w0 + dw];
    s.x += v.x; s.y += v.y; s.z += v.z; s.w += v.w;
  }
  ((float4*)Gh)[c2 * HDIM + t] = s;
  float4 s2 = make_float4(0, 0, 0, 0);
#pragma unroll
  for (int dh = 0; dh < 8; dh++) {
    float4 v = T4[(b * HDIM + w0 + dh) * WDIM + t];
    s2.x += v.x; s2.y += v.y; s2.z += v.z; s2.w += v.w;
  }
  ((float4*)Gw)[c2 * WDIM + t] = s2;
}

// K5: out = gamma*(aug_h + aug_w) + x.  grid 1024: (b, c, h-quarter)
__global__ __launch_bounds__(256) void k5_out(const float* __restrict__ x,
                                              const float* __restrict__ Ph,
                                              const float* __restrict__ Pw,
                                              const float* __restrict__ Gh,
                                              const float* __restrict__ Gw,
                                              const float* __restrict__ gamma,
                                              float* __restrict__ outb) {
  int bid = blockIdx.x;
  int hq = bid & 3, c = (bid >> 2) & 63, b = bid >> 8;
  int t = threadIdx.x;
  int tw = t & 127, th2 = t >> 7;
  float g = gamma[0];
  int c2h = (b * HDIM + tw) >> 3;
  float4 ph = ((const float4*)Ph)[c2h * 512 + (tw & 7) * 64 + c];
  const float* xp = x + (size_t)(b * CDIM + c) * PLANE;
  float* op = outb + (size_t)(b * CDIM + c) * PLANE;
#pragma unroll 4
  for (int j = 0; j < 16; j++) {
    int h = hq * 32 + j * 2 + th2;
    int c2w = (b * HDIM + h) >> 3;
    float4 pw = ((const float4*)Pw)[c2w * 512 + (h & 7) * 64 + c];
    float4 gh = ((const float4*)Gh)[c2h * HDIM + h];
    float4 gw = ((const float4*)Gw)[c2w * WDIM + tw];
    float val = ph.x * gh.x + ph.y * gh.y + ph.z * gh.z + ph.w * gh.w
              + pw.x * gw.x + pw.y * gw.y + pw.z * gw.z + pw.w * gw.w;
    op[h * WDIM + tw] = fmaf(g, val, xp[h * WDIM + tw]);
  }
}

// K6: 3x3 conv (SAME, no bias). block = (b, 8-o tile, 4-row strip), 256 thr.
// grid 1024 -> 4 blocks/CU, 4 waves/SIMD (was 1).
__global__ __launch_bounds__(256) void k6_conv(const float* __restrict__ outb,
                                               const float* __restrict__ Wc,
                                               float* __restrict__ yb) {
  __shared__ float strip[6 * WDIM];
  int bid = blockIdx.x;
  int hs = bid & 31, ot = (bid >> 5) & 7, b = bid >> 8;
  int hbase = hs * 4, obase = ot * 8;
  int t = threadIdx.x;
  int tw = t & 127, th2 = t >> 7;
  float acc[2][8];
#pragma unroll
  for (int k = 0; k < 2; k++)
#pragma unroll
    for (int o = 0; o < 8; o++) acc[k][o] = 0.f;

  const float* inb = outb + (size_t)b * CHW;
  float pre[3];
#pragma unroll
  for (int k = 0; k < 3; k++) {
    int idx = k * 256 + t; int row = idx >> 7, ww = idx & 127; int gh = hbase - 1 + row;
    pre[k] = (gh >= 0 && gh < HDIM) ? inb[gh * WDIM + ww] : 0.f;
  }
  for (int i = 0; i < CDIM; i++) {
    __syncthreads();
#pragma unroll
    for (int k = 0; k < 3; k++) strip[k * 256 + t] = pre[k];
    __syncthreads();
    if (i < CDIM - 1) {
      const float* np = inb + (size_t)(i + 1) * PLANE;
#pragma unroll
      for (int k = 0; k < 3; k++) {
        int idx = k * 256 + t; int row = idx >> 7, ww = idx & 127; int gh = hbase - 1 + row;
        pre[k] = (gh >= 0 && gh < HDIM) ? np[gh * WDIM + ww] : 0.f;
      }
    }
    float nb[5][3];
#pragma unroll
    for (int r = 0; r < 5; r++) {
      int row = th2 + r;
      nb[r][0] = (tw > 0)   ? strip[row * WDIM + tw - 1] : 0.f;
      nb[r][1] =              strip[row * WDIM + tw];
      nb[r][2] = (tw < 127) ? strip[row * WDIM + tw + 1] : 0.f;
    }
    const float* wp = Wc + ((size_t)obase * CDIM + i) * 9;
#pragma unroll
    for (int o = 0; o < 8; o++) {
      const float* w9 = wp + (size_t)o * CDIM * 9;
      float w0 = w9[0], w1 = w9[1], w2 = w9[2], w3 = w9[3], w4 = w9[4],
            w5 = w9[5], w6 = w9[6], w7 = w9[7], w8 = w9[8];
#pragma unroll
      for (int k = 0; k < 2; k++) {
        acc[k][o] += nb[2*k  ][0] * w0 + nb[2*k  ][1] * w1 + nb[2*k  ][2] * w2
                   + nb[2*k+1][0] * w3 + nb[2*k+1][1] * w4 + nb[2*k+1][2] * w5
                   + nb[2*k+2][0] * w6 + nb[2*k+2][1] * w7 + nb[2*k+2][2] * w8;
      }
    }
  }
#pragma unroll
  for (int k = 0; k < 2; k++) {
    int h = hbase + th2 + 2 * k;
#pragma unroll
    for (int o = 0; o < 8; o++)
      yb[((size_t)(b * CDIM + obase + o) * HDIM + h) * WDIM + tw] = acc[k][o];
  }
}

// K7a: per (b, o) plane partial sums for BN stats (512 thr, float4 loads)
__global__ __launch_bounds__(512) void k7a_stats(const float* __restrict__ yb,
                                                 float* __restrict__ part) {
  int bid = blockIdx.x;            // b*64 + o
  int t = threadIdx.x;             // 512
  const float4* yp = (const float4*)(yb + (size_t)bid * PLANE);
  float s = 0.f, ss = 0.f;
  for (int r = t; r < PLANE / 4; r += 512) {
    float4 v = yp[r];
    s  += v.x + v.y + v.z + v.w;
    ss += v.x * v.x + v.y * v.y + v.z * v.z + v.w * v.w;
  }
#pragma unroll
  for (int off = 32; off; off >>= 1) { s += __shfl_xor(s, off); ss += __shfl_xor(ss, off); }
  __shared__ float sh[16];
  int wid = t >> 6;
  if ((t & 63) == 0) { sh[wid] = s; sh[8 + wid] = ss; }
  __syncthreads();
  if (t == 0) {
    s = 0.f; ss = 0.f;
#pragma unroll
    for (int wv = 0; wv < 8; wv++) { s += sh[wv]; ss += sh[8 + wv]; }
    part[bid] = s;
    part[256 + bid] = ss;
  }
}

// K7b: finalize mean / rstd per channel
__global__ void k7b_finalize(const float* __restrict__ part, float* __restrict__ stats) {
  int o = threadIdx.x;             // 64
  float s = 0.f, ss = 0.f;
#pragma unroll
  for (int b = 0; b < BDIM; b++) { s += part[b * 64 + o]; ss += part[256 + b * 64 + o]; }
  float n = (float)(BDIM * PLANE);
  float m = s / n;
  float var = ss / n - m * m;
  stats[o] = m;
  stats[64 + o] = rsqrtf(var + 1e-5f);
}

// K8: normalize + affine + ReLU
__global__ void k8_norm(const float* __restrict__ yb, const float* __restrict__ stats,
                        const float* __restrict__ bnw, const float* __restrict__ bnb,
                        float* __restrict__ out) {
  int idx = blockIdx.x * 256 + threadIdx.x;   // float4 index, total 1048576
  int c = (idx >> 12) & 63;
  float4 v = ((const float4*)yb)[idx];
  float m = stats[c], rs = stats[64 + c], w = bnw[c], bb = bnb[c];
  v.x = fmaxf(0.f, (v.x - m) * rs * w + bb);
  v.y = fmaxf(0.f, (v.y - m) * rs * w + bb);
  v.z = fmaxf(0.f, (v.z - m) * rs * w + bb);
  v.w = fmaxf(0.f, (v.w - m) * rs * w + bb);
  ((float4*)out)[idx] = v;
}

extern "C" void kernel_launch(void* const* d_in, const int* in_sizes, int n_in,
                              void* d_out, int out_size, void* d_ws, size_t ws_size,
                              hipStream_t stream) {
  const float* x     = (const float*)d_in[0];
  const float* W1    = (const float*)d_in[1];
  const float* b1    = (const float*)d_in[2];
  const float* W2    = (const float*)d_in[3];
  const float* b2    = (const float*)d_in[4];
  const float* Wc    = (const float*)d_in[5];
  const float* bnw   = (const float*)d_in[6];
  const float* bnb   = (const float*)d_in[7];
  const float* gamma = (const float*)d_in[8];
  float* out = (float*)d_out;

  float* ws   = (float*)d_ws;
  float* T    = ws;                 // 262144
  float* xmw  = T    + 262144;      // 32768
  float* xmh  = xmw  + 32768;       // 32768
  float* ench = xmh  + 32768;       // 32768
  float* encw = ench + 32768;       // 32768
  float* Ph   = encw + 32768;       // 131072
  float* Pw   = Ph   + 131072;      // 131072
  float* Gh   = Pw   + 131072;      // 32768
  float* Gw   = Gh   + 32768;       // 32768
  float* outb = Gw   + 32768;       // 4194304
  float* yb   = outb + 4194304;     // 4194304
  float* part = yb   + 4194304;     // 512
  float* stats= part + 512;         // 128

  k1_T_rowmean<<<512, 256, 0, stream>>>(x, T, xmw);
  k2_colmean  <<<256, 256, 0, stream>>>(x, xmh);
  k3_enc      <<<256, 256, 0, stream>>>(W1, b1, W2, b2, xmw, xmh, ench, encw);
  k4_probs    <<<256, 256, 0, stream>>>(x, ench, encw, Ph, Pw);
  k4b_groups  <<<64, 128, 0, stream>>>(T, Gh, Gw);
  k5_out      <<<1024, 256, 0, stream>>>(x, Ph, Pw, Gh, Gw, gamma, outb);
  k6_conv     <<<1024, 256, 0, stream>>>(outb, Wc, yb);
  k7a_stats   <<<256, 512, 0, stream>>>(yb, part);
  k7b_finalize<<<1, 64, 0, stream>>>(part, stats);
  k8_norm     <<<4096, 256, 0, stream>>>(yb, stats, bnw, bnb, out);
}

// Round 4
// 170.993 us; speedup vs baseline: 1.8548x; 1.3089x over previous
//
#include <hip/hip_runtime.h>
#include <math.h>

#define BDIM 4
#define CDIM 64
#define HDIM 128
#define WDIM 128
#define PLANE (HDIM*WDIM)   // 16384
#define CHW (CDIM*PLANE)    // 1048576

typedef unsigned short ushort_t;
typedef short short8 __attribute__((ext_vector_type(8)));
typedef float floatx4 __attribute__((ext_vector_type(4)));

__device__ inline unsigned int pack_bf16(float lo, float hi) {
  unsigned int ul = __float_as_uint(lo);
  unsigned int uh = __float_as_uint(hi);
  unsigned int rl = (ul + 0x7FFFu + ((ul >> 16) & 1u)) >> 16;   // RNE
  unsigned int rh = (uh + 0x7FFFu + ((uh >> 16) & 1u)) >> 16;
  return (rh << 16) | (rl & 0xFFFFu);
}

// K1: per (b,h): channel-residue sums T[b][h][w][4] and row means xmw[b][c][h].
__global__ __launch_bounds__(256) void k1_T_rowmean(const float* __restrict__ x,
                                                    float* __restrict__ T,
                                                    float* __restrict__ xmw) {
  int bid = blockIdx.x;            // b*128 + h
  int b = bid >> 7, h = bid & 127;
  int t = threadIdx.x;
  int wid = t >> 6, lane = t & 63;
  const float* xp = x + (size_t)b * CHW + h * WDIM;
  float tr[4] = {0,0,0,0}, ur[4] = {0,0,0,0};
#pragma unroll
  for (int cc = 0; cc < 16; cc++) {
    int c = wid * 16 + cc;
    int k = cc & 3;
    float v0 = xp[c * PLANE + lane];
    float v1 = xp[c * PLANE + lane + 64];
    tr[k] += v0; ur[k] += v1;
    float s = v0 + v1;
#pragma unroll
    for (int off = 32; off; off >>= 1) s += __shfl_xor(s, off);
    if (lane == 0) xmw[(b * CDIM + c) * HDIM + h] = s * (1.f / WDIM);
  }
  __shared__ float4 pt[4][128];
  pt[wid][lane]      = make_float4(tr[0], tr[1], tr[2], tr[3]);
  pt[wid][lane + 64] = make_float4(ur[0], ur[1], ur[2], ur[3]);
  __syncthreads();
  if (t < 128) {
    float4 a = pt[0][t], bb = pt[1][t], cvec = pt[2][t], d = pt[3][t];
    float4 s = make_float4(a.x + bb.x + cvec.x + d.x, a.y + bb.y + cvec.y + d.y,
                           a.z + bb.z + cvec.z + d.z, a.w + bb.w + cvec.w + d.w);
    ((float4*)T)[(b * HDIM + h) * WDIM + t] = s;
  }
}

// K2: column means xmh[b][c][w]
__global__ void k2_colmean(const float* __restrict__ x, float* __restrict__ xmh) {
  int bid = blockIdx.x;
  int b = bid >> 6, c = bid & 63;
  int t = threadIdx.x;
  int tw = t & 127, th2 = t >> 7;
  const float* xp = x + (size_t)(b * CDIM + c) * PLANE;
  float s = 0.f;
  for (int h = th2 * 64; h < th2 * 64 + 64; h++) s += xp[h * WDIM + tw];
  __shared__ float sh[256];
  sh[t] = s;
  __syncthreads();
  if (t < 128) xmh[(b * CDIM + c) * WDIM + t] = (sh[t] + sh[t + 128]) * (1.f / HDIM);
}

// K3: enc
__global__ void k3_enc(const float* __restrict__ W1, const float* __restrict__ bias1,
                       const float* __restrict__ W2, const float* __restrict__ bias2,
                       const float* __restrict__ xmw, const float* __restrict__ xmh,
                       float* __restrict__ ench, float* __restrict__ encw) {
  int bid = blockIdx.x;
  int t = threadIdx.x;
  int o = t >> 2, bb = t & 3;
  if (bid < HDIM) {
    int h = bid;
    float s = bias1[o];
    for (int i = 0; i < CDIM; i++) s += W1[o * CDIM + i] * xmw[(bb * CDIM + i) * HDIM + h];
    ench[(o * HDIM + h) * 4 + bb] = s;
  } else {
    int w = bid - HDIM;
    float s = bias2[o];
    for (int i = 0; i < CDIM; i++) s += W2[o * CDIM + i] * xmh[(bb * CDIM + i) * WDIM + w];
    encw[(o * WDIM + w) * 4 + bb] = s;
  }
}

// K4: per (b,c) plane: 4-way softmax probs
__global__ __launch_bounds__(256) void k4_probs(const float* __restrict__ x,
                                                const float* __restrict__ ench,
                                                const float* __restrict__ encw,
                                                float* __restrict__ Ph,
                                                float* __restrict__ Pw) {
  __shared__ float plane[HDIM * WDIM];
  int bid = blockIdx.x;
  int b = bid >> 6, c = bid & 63;
  int t = threadIdx.x;
  const float* xp = x + (size_t)(b * CDIM + c) * PLANE;
#pragma unroll 4
  for (int j = 0; j < 64; j++) {
    int idx = j * 256 + t;
    int row = idx >> 7, col = idx & 127;
    plane[row * WDIM + (col ^ (row & 31))] = xp[idx];
  }
  __syncthreads();
  int half = t >> 7, p = t & 127;
  int c2 = (b * HDIM + p) >> 3;
  float e0 = 0, e1 = 0, e2 = 0, e3 = 0;
  if (half == 0) {
    const float4* E = (const float4*)ench + c2 * HDIM;
    for (int h = 0; h < HDIM; h++) {
      float v = plane[h * WDIM + (p ^ (h & 31))];
      float4 e = E[h];
      e0 += v * e.x; e1 += v * e.y; e2 += v * e.z; e3 += v * e.w;
    }
  } else {
    const float4* E = (const float4*)encw + c2 * WDIM;
    for (int w = 0; w < WDIM; w++) {
      float v = plane[p * WDIM + (w ^ (p & 31))];
      float4 e = E[w];
      e0 += v * e.x; e1 += v * e.y; e2 += v * e.z; e3 += v * e.w;
    }
  }
  float m = fmaxf(fmaxf(e0, e1), fmaxf(e2, e3));
  float p0 = expf(e0 - m), p1 = expf(e1 - m), p2 = expf(e2 - m), p3 = expf(e3 - m);
  float sc = 1.f / ((p0 + p1 + p2 + p3) * 128.f);
  float4* dst = (half == 0) ? (float4*)Ph : (float4*)Pw;
  dst[c2 * 512 + (p & 7) * 64 + c] = make_float4(p0 * sc, p1 * sc, p2 * sc, p3 * sc);
}

// K4b: group sums
__global__ void k4b_groups(const float* __restrict__ T, float* __restrict__ Gh,
                           float* __restrict__ Gw) {
  int c2 = blockIdx.x;
  int t = threadIdx.x;
  int b = c2 >> 4;
  int w0 = (c2 & 15) * 8;
  const float4* T4 = (const float4*)T;
  float4 s = make_float4(0, 0, 0, 0);
#pragma unroll
  for (int dw = 0; dw < 8; dw++) {
    float4 v = T4[(b * HDIM + t) * WDIM + w0 + dw];
    s.x += v.x; s.y += v.y; s.z += v.z; s.w += v.w;
  }
  ((float4*)Gh)[c2 * HDIM + t] = s;
  float4 s2 = make_float4(0, 0, 0, 0);
#pragma unroll
  for (int dh = 0; dh < 8; dh++) {
    float4 v = T4[(b * HDIM + w0 + dh) * WDIM + t];
    s2.x += v.x; s2.y += v.y; s2.z += v.z; s2.w += v.w;
  }
  ((float4*)Gw)[c2 * WDIM + t] = s2;
}

// K5: out = gamma*(aug_h + aug_w) + x
__global__ __launch_bounds__(256) void k5_out(const float* __restrict__ x,
                                              const float* __restrict__ Ph,
                                              const float* __restrict__ Pw,
                                              const float* __restrict__ Gh,
                                              const float* __restrict__ Gw,
                                              const float* __restrict__ gamma,
                                              float* __restrict__ outb) {
  int bid = blockIdx.x;
  int hq = bid & 3, c = (bid >> 2) & 63, b = bid >> 8;
  int t = threadIdx.x;
  int tw = t & 127, th2 = t >> 7;
  float g = gamma[0];
  int c2h = (b * HDIM + tw) >> 3;
  float4 ph = ((const float4*)Ph)[c2h * 512 + (tw & 7) * 64 + c];
  const float* xp = x + (size_t)(b * CDIM + c) * PLANE;
  float* op = outb + (size_t)(b * CDIM + c) * PLANE;
#pragma unroll 4
  for (int j = 0; j < 16; j++) {
    int h = hq * 32 + j * 2 + th2;
    int c2w = (b * HDIM + h) >> 3;
    float4 pw = ((const float4*)Pw)[c2w * 512 + (h & 7) * 64 + c];
    float4 gh = ((const float4*)Gh)[c2h * HDIM + h];
    float4 gw = ((const float4*)Gw)[c2w * WDIM + tw];
    float val = ph.x * gh.x + ph.y * gh.y + ph.z * gh.z + ph.w * gh.w
              + pw.x * gw.x + pw.y * gw.y + pw.z * gw.z + pw.w * gw.w;
    op[h * WDIM + tw] = fmaf(g, val, xp[h * WDIM + tw]);
  }
}

// K6prep: bake conv weights into MFMA A-fragment lane order (bf16).
// afrag[((tap*2+chunk)*4+m)*64 + lane] (short8): o=m*16+(lane&15),
// i=chunk*32+(lane>>4)*8+e, Wc[o][i][dh][dw], tap=dh*3+dw.
__global__ void k6_prep(const float* __restrict__ Wc, ushort_t* __restrict__ afrag) {
  int idx = blockIdx.x * 256 + threadIdx.x;   // 0..4607
  if (idx >= 4608) return;
  int lane = idx & 63;
  int m = (idx >> 6) & 3;
  int chunk = (idx >> 8) & 1;
  int tap = idx >> 9;
  int dh = tap / 3, dw = tap % 3;
  int o = m * 16 + (lane & 15);
  int ib = chunk * 32 + (lane >> 4) * 8;
  unsigned int d[4];
#pragma unroll
  for (int j = 0; j < 4; j++) {
    float lo = Wc[((size_t)(o * CDIM + ib + 2 * j) * 3 + dh) * 3 + dw];
    float hi = Wc[((size_t)(o * CDIM + ib + 2 * j + 1) * 3 + dh) * 3 + dw];
    d[j] = pack_bf16(lo, hi);
  }
  uint4* dst = (uint4*)afrag + idx;
  *dst = make_uint4(d[0], d[1], d[2], d[3]);
}

// K6: 3x3 conv via bf16 MFMA implicit GEMM.
// Block = (b, output row h0), 512 thr (8 waves). Wave wv owns n-tile w0=wv*16,
// all 4 m-tiles (o=0..63). K = 2 chunks x 9 taps x 32 i.
// LDS: bf16 [3 rows][130 wlp][32 i], granule (8 i) XOR-swizzled pg=g^((wlp>>1)&3).
__global__ __launch_bounds__(512) void k6_conv(const float* __restrict__ outb,
                                               const ushort_t* __restrict__ afrag,
                                               float* __restrict__ yb) {
  __shared__ uint4 lds_in[3 * 130 * 4];   // 3*130*4 granules * 16B = 24960 B
  int bid = blockIdx.x;
  int b = bid >> 7, h0 = bid & 127;
  int t = threadIdx.x;
  int lane = t & 63, wv = t >> 6;
  int w0 = wv * 16;
  const float* inb = outb + (size_t)b * CHW;

  floatx4 acc[4];
#pragma unroll
  for (int m = 0; m < 4; m++) acc[m] = (floatx4){0.f, 0.f, 0.f, 0.f};

  for (int chunk = 0; chunk < 2; chunk++) {
    int i0 = chunk * 32;
    __syncthreads();                       // prior readers done before restage
    // ---- stage fp32 -> bf16 LDS (reg-staged, swizzled ds_write_b128) ----
#pragma unroll
    for (int k = 0; k < 4; k++) {
      int gid = k * 512 + t;
      if (gid < 1560) {
        int wlp = gid % 130;
        int rest = gid / 130;
        int g = rest & 3, lr = rest >> 2;
        int h = h0 - 1 + lr, wl = wlp - 1;
        unsigned int d0 = 0, d1 = 0, d2 = 0, d3 = 0;
        if (h >= 0 && h < HDIM && wl >= 0 && wl < WDIM) {
          const float* sp = inb + (size_t)(i0 + g * 8) * PLANE + h * WDIM + wl;
          float v0 = sp[0], v1 = sp[PLANE], v2 = sp[2 * PLANE], v3 = sp[3 * PLANE];
          float v4 = sp[4 * PLANE], v5 = sp[5 * PLANE], v6 = sp[6 * PLANE], v7 = sp[7 * PLANE];
          d0 = pack_bf16(v0, v1); d1 = pack_bf16(v2, v3);
          d2 = pack_bf16(v4, v5); d3 = pack_bf16(v6, v7);
        }
        int pg = g ^ ((wlp >> 1) & 3);
        lds_in[(lr * 130 + wlp) * 4 + pg] = make_uint4(d0, d1, d2, d3);
      }
    }
    __syncthreads();
    // ---- compute: 9 taps x (1 ds_read_b128 + 4 A-loads + 4 MFMA) ----
#pragma unroll
    for (int tap = 0; tap < 9; tap++) {
      int lr = tap / 3, dw = tap % 3;
      int wlp = w0 + (lane & 15) + dw;
      int pg = (lane >> 4) ^ ((wlp >> 1) & 3);
      short8 bf = *(const short8*)&lds_in[(lr * 130 + wlp) * 4 + pg];
      const short8* ap = (const short8*)afrag + (size_t)((tap * 2 + chunk) * 4) * 64 + lane;
#pragma unroll
      for (int m = 0; m < 4; m++) {
        short8 a = ap[m * 64];
        acc[m] = __builtin_amdgcn_mfma_f32_16x16x32_bf16(a, bf, acc[m], 0, 0, 0);
      }
    }
  }
  // ---- epilogue: C/D layout col=lane&15, row=(lane>>4)*4+j ----
  int col = lane & 15, rg = lane >> 4;
#pragma unroll
  for (int m = 0; m < 4; m++) {
#pragma unroll
    for (int j = 0; j < 4; j++) {
      int o = m * 16 + rg * 4 + j;
      yb[((size_t)(b * CDIM + o) * HDIM + h0) * WDIM + w0 + col] = acc[m][j];
    }
  }
}

// K7a: per (b, o) plane partial sums for BN stats
__global__ __launch_bounds__(512) void k7a_stats(const float* __restrict__ yb,
                                                 float* __restrict__ part) {
  int bid = blockIdx.x;
  int t = threadIdx.x;
  const float4* yp = (const float4*)(yb + (size_t)bid * PLANE);
  float s = 0.f, ss = 0.f;
  for (int r = t; r < PLANE / 4; r += 512) {
    float4 v = yp[r];
    s  += v.x + v.y + v.z + v.w;
    ss += v.x * v.x + v.y * v.y + v.z * v.z + v.w * v.w;
  }
#pragma unroll
  for (int off = 32; off; off >>= 1) { s += __shfl_xor(s, off); ss += __shfl_xor(ss, off); }
  __shared__ float sh[16];
  int wid = t >> 6;
  if ((t & 63) == 0) { sh[wid] = s; sh[8 + wid] = ss; }
  __syncthreads();
  if (t == 0) {
    s = 0.f; ss = 0.f;
#pragma unroll
    for (int wv = 0; wv < 8; wv++) { s += sh[wv]; ss += sh[8 + wv]; }
    part[bid] = s;
    part[256 + bid] = ss;
  }
}

// K7b: finalize mean / rstd per channel
__global__ void k7b_finalize(const float* __restrict__ part, float* __restrict__ stats) {
  int o = threadIdx.x;
  float s = 0.f, ss = 0.f;
#pragma unroll
  for (int b = 0; b < BDIM; b++) { s += part[b * 64 + o]; ss += part[256 + b * 64 + o]; }
  float n = (float)(BDIM * PLANE);
  float m = s / n;
  float var = ss / n - m * m;
  stats[o] = m;
  stats[64 + o] = rsqrtf(var + 1e-5f);
}

// K8: normalize + affine + ReLU
__global__ void k8_norm(const float* __restrict__ yb, const float* __restrict__ stats,
                        const float* __restrict__ bnw, const float* __restrict__ bnb,
                        float* __restrict__ out) {
  int idx = blockIdx.x * 256 + threadIdx.x;
  int c = (idx >> 12) & 63;
  float4 v = ((const float4*)yb)[idx];
  float m = stats[c], rs = stats[64 + c], w = bnw[c], bb = bnb[c];
  v.x = fmaxf(0.f, (v.x - m) * rs * w + bb);
  v.y = fmaxf(0.f, (v.y - m) * rs * w + bb);
  v.z = fmaxf(0.f, (v.z - m) * rs * w + bb);
  v.w = fmaxf(0.f, (v.w - m) * rs * w + bb);
  ((float4*)out)[idx] = v;
}

extern "C" void kernel_launch(void* const* d_in, const int* in_sizes, int n_in,
                              void* d_out, int out_size, void* d_ws, size_t ws_size,
                              hipStream_t stream) {
  const float* x     = (const float*)d_in[0];
  const float* W1    = (const float*)d_in[1];
  const float* b1    = (const float*)d_in[2];
  const float* W2    = (const float*)d_in[3];
  const float* b2    = (const float*)d_in[4];
  const float* Wc    = (const float*)d_in[5];
  const float* bnw   = (const float*)d_in[6];
  const float* bnb   = (const float*)d_in[7];
  const float* gamma = (const float*)d_in[8];
  float* out = (float*)d_out;

  float* ws   = (float*)d_ws;
  float* T    = ws;                 // 262144
  float* xmw  = T    + 262144;      // 32768
  float* xmh  = xmw  + 32768;       // 32768
  float* ench = xmh  + 32768;       // 32768
  float* encw = ench + 32768;       // 32768
  float* Ph   = encw + 32768;       // 131072
  float* Pw   = Ph   + 131072;      // 131072
  float* Gh   = Pw   + 131072;      // 32768
  float* Gw   = Gh   + 32768;       // 32768
  float* outb = Gw   + 32768;       // 4194304
  float* yb   = outb + 4194304;     // 4194304
  float* part = yb   + 4194304;     // 512
  float* stats= part + 512;         // 128
  ushort_t* afrag = (ushort_t*)(stats + 128);   // 36864 ushorts (18432 floats)

  k6_prep     <<<18, 256, 0, stream>>>(Wc, afrag);
  k1_T_rowmean<<<512, 256, 0, stream>>>(x, T, xmw);
  k2_colmean  <<<256, 256, 0, stream>>>(x, xmh);
  k3_enc      <<<256, 256, 0, stream>>>(W1, b1, W2, b2, xmw, xmh, ench, encw);
  k4_probs    <<<256, 256, 0, stream>>>(x, ench, encw, Ph, Pw);
  k4b_groups  <<<64, 128, 0, stream>>>(T, Gh, Gw);
  k5_out      <<<1024, 256, 0, stream>>>(x, Ph, Pw, Gh, Gw, gamma, outb);
  k6_conv     <<<512, 512, 0, stream>>>(outb, afrag, yb);
  k7a_stats   <<<256, 512, 0, stream>>>(yb, part);
  k7b_finalize<<<1, 64, 0, stream>>>(part, stats);
  k8_norm     <<<4096, 256, 0, stream>>>(yb, stats, bnw, bnb, out);
}